// Round 5
// baseline (302.803 us; speedup 1.0000x reference)
//
#include <hip/hip_runtime.h>
#include <hip/hip_bf16.h>
#include <hip/hip_fp16.h>
#include <math.h>

#define NFEAT 128
#define NCLS  64
#define WPAD  132           // W row stride in floats (float4-aligned pad)
#define RQ    16            // uint4 per fp16 row (128*2/16)

// ---------- helpers ----------

typedef unsigned int u32x4 __attribute__((ext_vector_type(4)));

// non-temporal 16B load: bypass/evict-first in L1 (rows have no L1 locality;
// theory: routes around the per-CU L1 miss-tracking cap that serializes gathers)
__device__ __forceinline__ uint4 ldnt(const uint4* p) {
    u32x4 v = __builtin_nontemporal_load((const u32x4*)p);
    uint4 r; r.x = v.x; r.y = v.y; r.z = v.z; r.w = v.w;
    return r;
}

__device__ __forceinline__ void accum_h8(float acc[8], uint4 v) {
    union { uint4 u; __half2 h[4]; } c; c.u = v;
    #pragma unroll
    for (int t = 0; t < 4; ++t) {
        float2 f = __half22float2(c.h[t]);
        acc[2 * t]     += f.x;
        acc[2 * t + 1] += f.y;
    }
}

// ---------- graph build ----------

__global__ void count_kernel(const int* __restrict__ dst, int* __restrict__ cnt, int E) {
    int e4 = blockIdx.x * blockDim.x + threadIdx.x;     // 4 edges per thread
    if (e4 * 4 + 3 < E) {
        int4 d = ((const int4*)dst)[e4];
        atomicAdd(&cnt[d.x], 1); atomicAdd(&cnt[d.y], 1);
        atomicAdd(&cnt[d.z], 1); atomicAdd(&cnt[d.w], 1);
    } else {
        for (int e = e4 * 4; e < E; ++e) atomicAdd(&cnt[dst[e]], 1);
    }
}

__global__ void scan_local(const int* __restrict__ cnt, int* __restrict__ row_ptr,
                           int* __restrict__ bsums, int n) {
    __shared__ int lds[256];
    const int tid = threadIdx.x;
    int i = blockIdx.x * 256 + tid;
    int v = (i < n) ? cnt[i] : 0;
    lds[tid] = v;
    __syncthreads();
    for (int off = 1; off < 256; off <<= 1) {
        int t = (tid >= off) ? lds[tid - off] : 0;
        __syncthreads();
        lds[tid] += t;
        __syncthreads();
    }
    if (i < n) row_ptr[i + 1] = lds[tid];          // local inclusive scan
    if (tid == 255) bsums[blockIdx.x] = lds[255];  // raw block total
}

// finalize with fused block-offset reduction (nb <= 256 blocks)
__global__ void scan_finalize(const int* __restrict__ cnt, const int* __restrict__ bsums,
                              int* __restrict__ row_ptr, int* __restrict__ cursor,
                              float* __restrict__ dinv, int n) {
    __shared__ int wsum[4];
    const int tid = threadIdx.x;
    int v = (tid < blockIdx.x) ? bsums[tid] : 0;   // sum of totals of prior blocks
    for (int o = 32; o > 0; o >>= 1) v += __shfl_xor(v, o);
    if ((tid & 63) == 0) wsum[tid >> 6] = v;
    __syncthreads();
    int off = wsum[0] + wsum[1] + wsum[2] + wsum[3];

    int i = blockIdx.x * 256 + tid;
    if (i < n) {
        int incl = row_ptr[i + 1] + off;
        row_ptr[i + 1] = incl;
        int c = cnt[i];
        cursor[i] = incl - c;
        dinv[i] = rsqrtf((float)c + 1.0f);         // +1 self-loop
        if (i == 0) row_ptr[0] = 0;
    }
}

__global__ void scatter_kernel(const int* __restrict__ src, const int* __restrict__ dst,
                               int* __restrict__ cursor, int* __restrict__ csr, int E) {
    int e4 = blockIdx.x * blockDim.x + threadIdx.x;
    if (e4 * 4 + 3 < E) {
        int4 s = ((const int4*)src)[e4];
        int4 d = ((const int4*)dst)[e4];
        csr[atomicAdd(&cursor[d.x], 1)] = s.x;
        csr[atomicAdd(&cursor[d.y], 1)] = s.y;
        csr[atomicAdd(&cursor[d.z], 1)] = s.z;
        csr[atomicAdd(&cursor[d.w], 1)] = s.w;
    } else {
        for (int e = e4 * 4; e < E; ++e)
            csr[atomicAdd(&cursor[dst[e]], 1)] = src[e];
    }
}

// ---------- prep: xh[j] = dinv[j] * x[j] as fp16 ----------
__global__ void prep_kernel(const float* __restrict__ x, const float* __restrict__ dinv,
                            __half* __restrict__ xh, int total4) {   // total4 = N*32
    int idx = blockIdx.x * blockDim.x + threadIdx.x;
    if (idx < total4) {
        float d = dinv[idx >> 5];                 // 32 quads per node
        float4 v = ((const float4*)x)[idx];
        union { uint2 u; __half2 h[2]; } r;
        r.h[0] = __floats2half2_rn(d * v.x, d * v.y);
        r.h[1] = __floats2half2_rn(d * v.z, d * v.w);
        ((uint2*)xh)[idx] = r.u;
    }
}

// ---------- shared gather core: 16-edge unroll, 4 NT row-loads in flight, ----------
// ---------- index prefetch pipelined behind accumulate, predicated tail ----------
__device__ __forceinline__ void gather_row(float acc[8], const uint4* __restrict__ X,
                                           const int* __restrict__ csr,
                                           int ks, int ke, int sub, int q) {
    int k = ks;
    int j0, j1, j2, j3;
    bool have = (k + 16 <= ke);
    if (have) {
        j0 = csr[k + sub]; j1 = csr[k + 4 + sub];
        j2 = csr[k + 8 + sub]; j3 = csr[k + 12 + sub];
    }
    while (have) {
        uint4 v0 = ldnt(&X[(size_t)j0 * RQ + q]);
        uint4 v1 = ldnt(&X[(size_t)j1 * RQ + q]);
        uint4 v2 = ldnt(&X[(size_t)j2 * RQ + q]);
        uint4 v3 = ldnt(&X[(size_t)j3 * RQ + q]);
        k += 16;
        have = (k + 16 <= ke);
        if (have) {                               // prefetch next indices while v* in flight
            j0 = csr[k + sub]; j1 = csr[k + 4 + sub];
            j2 = csr[k + 8 + sub]; j3 = csr[k + 12 + sub];
        }
        accum_h8(acc, v0); accum_h8(acc, v1);
        accum_h8(acc, v2); accum_h8(acc, v3);
    }
    // tail: 0..15 edges, 4 independent exec-masked load chains
    if (k + sub < ke)      accum_h8(acc, ldnt(&X[(size_t)csr[k + sub] * RQ + q]));
    if (k + 4 + sub < ke)  accum_h8(acc, ldnt(&X[(size_t)csr[k + 4 + sub] * RQ + q]));
    if (k + 8 + sub < ke)  accum_h8(acc, ldnt(&X[(size_t)csr[k + 8 + sub] * RQ + q]));
    if (k + 12 + sub < ke) accum_h8(acc, ldnt(&X[(size_t)csr[k + 12 + sub] * RQ + q]));
}

// ---------- hop 1: y1h[i] = fp16( dinv[i]^2 * (sum_j xh[j] + xh[i]) ) ----------
__global__ __launch_bounds__(512) void hop1_kernel(const __half* __restrict__ xh,
                                                   const float* __restrict__ dinv,
                                                   const int* __restrict__ row_ptr,
                                                   const int* __restrict__ csr,
                                                   __half* __restrict__ y1h, int N) {
    const int tid = threadIdx.x;
    const int w = tid >> 6, lane = tid & 63;
    const int i = blockIdx.x * 8 + w;
    if (i >= N) return;                           // wave-uniform; no barriers
    const int sub = lane >> 4;
    const int q = lane & 15;
    const uint4* X = (const uint4*)xh;

    float acc[8] = {0.f, 0.f, 0.f, 0.f, 0.f, 0.f, 0.f, 0.f};
    int ks = row_ptr[i], ke = row_ptr[i + 1];
    gather_row(acc, X, csr, ks, ke, sub, q);
    if (sub == 0) accum_h8(acc, ldnt(&X[(size_t)i * RQ + q]));   // self: xh[i] = dinv[i]*x[i]

    #pragma unroll
    for (int t = 0; t < 8; ++t) {
        acc[t] += __shfl_xor(acc[t], 16);
        acc[t] += __shfl_xor(acc[t], 32);
    }

    if (sub == 0) {
        float di = dinv[i];
        float s = di * di;
        union { uint4 u; __half2 h[4]; } r;
        #pragma unroll
        for (int t = 0; t < 4; ++t)
            r.h[t] = __floats2half2_rn(s * acc[2 * t], s * acc[2 * t + 1]);
        ((uint4*)y1h)[(size_t)i * RQ + q] = r.u;
    }
}

// ---------- hop 2 fused with linear + log_softmax ----------
__global__ __launch_bounds__(512) void hop2_cls_kernel(const __half* __restrict__ y1h,
                                                       const float* __restrict__ dinv,
                                                       const int* __restrict__ row_ptr,
                                                       const int* __restrict__ csr,
                                                       const float* __restrict__ W,
                                                       const float* __restrict__ b,
                                                       float* __restrict__ out, int N) {
    __shared__ __align__(16) float Wl[NCLS * WPAD];   // 33 KB, padded rows
    __shared__ float bl[NCLS];
    __shared__ __align__(16) float h[8][NFEAT];

    const int tid = threadIdx.x;
    for (int t = tid; t < NCLS * NFEAT; t += 512) {
        int r = t >> 7, c = t & 127;
        Wl[r * WPAD + c] = W[t];
    }
    if (tid < NCLS) bl[tid] = b[tid];

    const int w = tid >> 6, lane = tid & 63;
    const int i = blockIdx.x * 8 + w;
    const int sub = lane >> 4;
    const int q = lane & 15;
    const uint4* Y = (const uint4*)y1h;

    if (i < N) {
        float acc[8] = {0.f, 0.f, 0.f, 0.f, 0.f, 0.f, 0.f, 0.f};
        int ks = row_ptr[i], ke = row_ptr[i + 1];
        gather_row(acc, Y, csr, ks, ke, sub, q);
        if (sub == 0) accum_h8(acc, ldnt(&Y[(size_t)i * RQ + q]));   // self term

        #pragma unroll
        for (int t = 0; t < 8; ++t) {
            acc[t] += __shfl_xor(acc[t], 16);
            acc[t] += __shfl_xor(acc[t], 32);
        }

        if (sub == 0) {                            // x2 = dinv[i] * (sum)
            float di = dinv[i];
            float4 r0 = {di * acc[0], di * acc[1], di * acc[2], di * acc[3]};
            float4 r1 = {di * acc[4], di * acc[5], di * acc[6], di * acc[7]};
            ((float4*)h[w])[2 * q]     = r0;
            ((float4*)h[w])[2 * q + 1] = r1;
        }
    }
    __syncthreads();

    if (i < N) {
        float dot = bl[lane];
        const float4* hr = (const float4*)h[w];                  // broadcast
        const float4* wr = (const float4*)(Wl + lane * WPAD);
        #pragma unroll
        for (int t = 0; t < NFEAT / 4; ++t) {
            float4 hv = hr[t], wv = wr[t];
            dot = fmaf(hv.x, wv.x, dot); dot = fmaf(hv.y, wv.y, dot);
            dot = fmaf(hv.z, wv.z, dot); dot = fmaf(hv.w, wv.w, dot);
        }
        float m = dot;
        for (int o = 32; o > 0; o >>= 1) m = fmaxf(m, __shfl_xor(m, o));
        float ex = __expf(dot - m);
        float se = ex;
        for (int o = 32; o > 0; o >>= 1) se += __shfl_xor(se, o);
        out[(size_t)i * NCLS + lane] = dot - m - logf(se);
    }
}

// ---------- launch ----------

static inline size_t align256(size_t v) { return (v + 255) & ~(size_t)255; }

extern "C" void kernel_launch(void* const* d_in, const int* in_sizes, int n_in,
                              void* d_out, int out_size, void* d_ws, size_t ws_size,
                              hipStream_t stream) {
    const float* x  = (const float*)d_in[0];
    const int*   ei = (const int*)d_in[1];
    const float* W  = (const float*)d_in[2];
    const float* b  = (const float*)d_in[3];
    float* out = (float*)d_out;

    const int N = in_sizes[0] / NFEAT;   // 50000
    const int E = in_sizes[1] / 2;       // 800000
    const int* src = ei;
    const int* dst = ei + E;
    const int NB = (N + 255) / 256;      // scan blocks (196 <= 256)

    char* ws = (char*)d_ws;
    size_t o = 0;
    int*    cnt     = (int*)(ws + o);    o += align256((size_t)N * 4);
    float*  dinv    = (float*)(ws + o);  o += align256((size_t)N * 4);
    int*    row_ptr = (int*)(ws + o);    o += align256((size_t)(N + 1) * 4);
    int*    cursor  = (int*)(ws + o);    o += align256((size_t)N * 4);
    int*    bsums   = (int*)(ws + o);    o += align256(256 * 4);
    int*    csr     = (int*)(ws + o);    o += align256((size_t)E * 4 + 256);
    __half* xh      = (__half*)(ws + o); o += align256((size_t)N * NFEAT * 2);
    __half* y1h     = (__half*)(ws + o); o += align256((size_t)N * NFEAT * 2);

    const int E4 = (E + 3) / 4;

    hipMemsetAsync(cnt, 0, (size_t)N * 4, stream);
    count_kernel<<<(E4 + 255) / 256, 256, 0, stream>>>(dst, cnt, E);
    scan_local<<<NB, 256, 0, stream>>>(cnt, row_ptr, bsums, N);
    scan_finalize<<<NB, 256, 0, stream>>>(cnt, bsums, row_ptr, cursor, dinv, N);
    scatter_kernel<<<(E4 + 255) / 256, 256, 0, stream>>>(src, dst, cursor, csr, E);
    prep_kernel<<<(N * 32 + 255) / 256, 256, 0, stream>>>(x, dinv, xh, N * 32);
    hop1_kernel<<<(N + 7) / 8, 512, 0, stream>>>(xh, dinv, row_ptr, csr, y1h, N);
    hop2_cls_kernel<<<(N + 7) / 8, 512, 0, stream>>>(y1h, dinv, row_ptr, csr, W, b, out, N);
}

// Round 6
// 268.360 us; speedup vs baseline: 1.1283x; 1.1283x over previous
//
#include <hip/hip_runtime.h>
#include <hip/hip_bf16.h>
#include <hip/hip_fp16.h>
#include <math.h>

#define NFEAT 128
#define NCLS  64
#define WPAD  132           // W row stride in floats (float4-aligned pad)
#define RQ    16            // uint4 per fp16 row (128*2/16)

// ---------- helpers ----------

__device__ __forceinline__ void accum_h8(float acc[8], uint4 v) {
    union { uint4 u; __half2 h[4]; } c; c.u = v;
    #pragma unroll
    for (int t = 0; t < 4; ++t) {
        float2 f = __half22float2(c.h[t]);
        acc[2 * t]     += f.x;
        acc[2 * t + 1] += f.y;
    }
}

// ---------- graph build ----------

__global__ void count_kernel(const int* __restrict__ dst, int* __restrict__ cnt, int E) {
    int e4 = blockIdx.x * blockDim.x + threadIdx.x;     // 4 edges per thread
    if (e4 * 4 + 3 < E) {
        int4 d = ((const int4*)dst)[e4];
        atomicAdd(&cnt[d.x], 1); atomicAdd(&cnt[d.y], 1);
        atomicAdd(&cnt[d.z], 1); atomicAdd(&cnt[d.w], 1);
    } else {
        for (int e = e4 * 4; e < E; ++e) atomicAdd(&cnt[dst[e]], 1);
    }
}

// scan over PADDED counts (round up to multiple of 4): row lengths in csr are 4-aligned
__global__ void scan_local(const int* __restrict__ cnt, int* __restrict__ row_ptr,
                           int* __restrict__ bsums, int n) {
    __shared__ int lds[256];
    const int tid = threadIdx.x;
    int i = blockIdx.x * 256 + tid;
    int v = (i < n) ? ((cnt[i] + 3) & ~3) : 0;
    lds[tid] = v;
    __syncthreads();
    for (int off = 1; off < 256; off <<= 1) {
        int t = (tid >= off) ? lds[tid - off] : 0;
        __syncthreads();
        lds[tid] += t;
        __syncthreads();
    }
    if (i < n) row_ptr[i + 1] = lds[tid];          // local inclusive scan (padded)
    if (tid == 255) bsums[blockIdx.x] = lds[255];  // raw block total
}

// finalize with fused block-offset reduction (nb <= 256 blocks)
__global__ void scan_finalize(const int* __restrict__ cnt, const int* __restrict__ bsums,
                              int* __restrict__ row_ptr, int* __restrict__ cursor,
                              float* __restrict__ dinv, int n) {
    __shared__ int wsum[4];
    const int tid = threadIdx.x;
    int v = (tid < blockIdx.x) ? bsums[tid] : 0;   // sum of totals of prior blocks
    for (int o = 32; o > 0; o >>= 1) v += __shfl_xor(v, o);
    if ((tid & 63) == 0) wsum[tid >> 6] = v;
    __syncthreads();
    int off = wsum[0] + wsum[1] + wsum[2] + wsum[3];

    int i = blockIdx.x * 256 + tid;
    if (i < n) {
        int incl = row_ptr[i + 1] + off;           // padded inclusive
        row_ptr[i + 1] = incl;
        int c = cnt[i];
        int cp = (c + 3) & ~3;
        cursor[i] = incl - cp;                     // row start; pads land at row end
        dinv[i] = rsqrtf((float)c + 1.0f);         // +1 self-loop (true degree)
        if (i == 0) row_ptr[0] = 0;
    }
}

// fill padded csr with the dummy node index N (its feature row is all-zero)
__global__ void fill_kernel(int* __restrict__ csr, int val, int total4) {
    int idx = blockIdx.x * blockDim.x + threadIdx.x;
    if (idx < total4) {
        int4 v = {val, val, val, val};
        ((int4*)csr)[idx] = v;
    }
}

__global__ void scatter_kernel(const int* __restrict__ src, const int* __restrict__ dst,
                               int* __restrict__ cursor, int* __restrict__ csr, int E) {
    int e4 = blockIdx.x * blockDim.x + threadIdx.x;
    if (e4 * 4 + 3 < E) {
        int4 s = ((const int4*)src)[e4];
        int4 d = ((const int4*)dst)[e4];
        csr[atomicAdd(&cursor[d.x], 1)] = s.x;
        csr[atomicAdd(&cursor[d.y], 1)] = s.y;
        csr[atomicAdd(&cursor[d.z], 1)] = s.z;
        csr[atomicAdd(&cursor[d.w], 1)] = s.w;
    } else {
        for (int e = e4 * 4; e < E; ++e)
            csr[atomicAdd(&cursor[dst[e]], 1)] = src[e];
    }
}

// ---------- prep: xh[j] = dinv[j] * x[j] as fp16 ----------
__global__ void prep_kernel(const float* __restrict__ x, const float* __restrict__ dinv,
                            __half* __restrict__ xh, int total4) {   // total4 = N*32
    int idx = blockIdx.x * blockDim.x + threadIdx.x;
    if (idx < total4) {
        float d = dinv[idx >> 5];                 // 32 quads per node
        float4 v = ((const float4*)x)[idx];
        union { uint2 u; __half2 h[2]; } r;
        r.h[0] = __floats2half2_rn(d * v.x, d * v.y);
        r.h[1] = __floats2half2_rn(d * v.z, d * v.w);
        ((uint2*)xh)[idx] = r.u;
    }
}

// zero the dummy row (row N) of an fp16 matrix
__global__ void zero_row_kernel(__half* __restrict__ m, int row) {
    ((uint4*)(m + (size_t)row * NFEAT))[threadIdx.x] = uint4{0, 0, 0, 0};  // 16 threads
}

// ---------- gather core ----------
// Rows padded to multiple of 4 (pads = dummy index Nd -> zero row, L1-hot).
// Main: 16-edge batches, 4 row-loads in flight, index prefetch.
// Tail: remainder in {0,4,8,12} edges, wave-uniform; absent groups cndmask'd
// to Nd so all 3 row loads issue back-to-back -> ONE latency exposure.
__device__ __forceinline__ void gather_row(float acc[8], const uint4* __restrict__ X,
                                           const int* __restrict__ csr,
                                           int ks, int ke, int sub, int q, int Nd) {
    int k = ks;
    int j0, j1, j2, j3;
    bool have = (k + 16 <= ke);
    if (have) {
        j0 = csr[k + sub]; j1 = csr[k + 4 + sub];
        j2 = csr[k + 8 + sub]; j3 = csr[k + 12 + sub];
    }
    while (have) {
        uint4 v0 = X[(size_t)j0 * RQ + q];
        uint4 v1 = X[(size_t)j1 * RQ + q];
        uint4 v2 = X[(size_t)j2 * RQ + q];
        uint4 v3 = X[(size_t)j3 * RQ + q];
        k += 16;
        have = (k + 16 <= ke);
        if (have) {                               // prefetch next indices while v* in flight
            j0 = csr[k + sub]; j1 = csr[k + 4 + sub];
            j2 = csr[k + 8 + sub]; j3 = csr[k + 12 + sub];
        }
        accum_h8(acc, v0); accum_h8(acc, v1);
        accum_h8(acc, v2); accum_h8(acc, v3);
    }
    int rem = (ke - k) >> 2;                      // 0..3, wave-uniform
    if (rem) {
        // csr reads up to k+11 may overrun this row into the next row / fill
        // region (allocation has slack) -> always valid node ids; absent
        // groups are redirected to the zero dummy row.
        int t0 = csr[k + sub];
        int t1 = csr[k + 4 + sub];
        int t2 = csr[k + 8 + sub];
        if (rem < 2) t1 = Nd;
        if (rem < 3) t2 = Nd;
        uint4 v0 = X[(size_t)t0 * RQ + q];
        uint4 v1 = X[(size_t)t1 * RQ + q];
        uint4 v2 = X[(size_t)t2 * RQ + q];
        accum_h8(acc, v0); accum_h8(acc, v1); accum_h8(acc, v2);
    }
}

// ---------- hop 1: y1h[i] = fp16( dinv[i]^2 * (sum_j xh[j] + xh[i]) ) ----------
__global__ __launch_bounds__(512) void hop1_kernel(const __half* __restrict__ xh,
                                                   const float* __restrict__ dinv,
                                                   const int* __restrict__ row_ptr,
                                                   const int* __restrict__ csr,
                                                   __half* __restrict__ y1h, int N) {
    const int tid = threadIdx.x;
    const int w = tid >> 6, lane = tid & 63;
    const int i = blockIdx.x * 8 + w;
    if (i >= N) return;                           // wave-uniform; no barriers
    const int sub = lane >> 4;
    const int q = lane & 15;
    const uint4* X = (const uint4*)xh;

    float acc[8] = {0.f, 0.f, 0.f, 0.f, 0.f, 0.f, 0.f, 0.f};
    int ks = row_ptr[i], ke = row_ptr[i + 1];
    gather_row(acc, X, csr, ks, ke, sub, q, N);
    if (sub == 0) accum_h8(acc, X[(size_t)i * RQ + q]);   // self: xh[i] = dinv[i]*x[i]

    #pragma unroll
    for (int t = 0; t < 8; ++t) {
        acc[t] += __shfl_xor(acc[t], 16);
        acc[t] += __shfl_xor(acc[t], 32);
    }

    if (sub == 0) {
        float di = dinv[i];
        float s = di * di;
        union { uint4 u; __half2 h[4]; } r;
        #pragma unroll
        for (int t = 0; t < 4; ++t)
            r.h[t] = __floats2half2_rn(s * acc[2 * t], s * acc[2 * t + 1]);
        ((uint4*)y1h)[(size_t)i * RQ + q] = r.u;
    }
}

// ---------- hop 2 fused with linear + log_softmax ----------
__global__ __launch_bounds__(512) void hop2_cls_kernel(const __half* __restrict__ y1h,
                                                       const float* __restrict__ dinv,
                                                       const int* __restrict__ row_ptr,
                                                       const int* __restrict__ csr,
                                                       const float* __restrict__ W,
                                                       const float* __restrict__ b,
                                                       float* __restrict__ out, int N) {
    __shared__ __align__(16) float Wl[NCLS * WPAD];   // 33 KB, padded rows
    __shared__ float bl[NCLS];
    __shared__ __align__(16) float h[8][NFEAT];

    const int tid = threadIdx.x;
    for (int t = tid; t < NCLS * NFEAT; t += 512) {
        int r = t >> 7, c = t & 127;
        Wl[r * WPAD + c] = W[t];
    }
    if (tid < NCLS) bl[tid] = b[tid];

    const int w = tid >> 6, lane = tid & 63;
    const int i = blockIdx.x * 8 + w;
    const int sub = lane >> 4;
    const int q = lane & 15;
    const uint4* Y = (const uint4*)y1h;

    if (i < N) {
        float acc[8] = {0.f, 0.f, 0.f, 0.f, 0.f, 0.f, 0.f, 0.f};
        int ks = row_ptr[i], ke = row_ptr[i + 1];
        gather_row(acc, Y, csr, ks, ke, sub, q, N);
        if (sub == 0) accum_h8(acc, Y[(size_t)i * RQ + q]);   // self term

        #pragma unroll
        for (int t = 0; t < 8; ++t) {
            acc[t] += __shfl_xor(acc[t], 16);
            acc[t] += __shfl_xor(acc[t], 32);
        }

        if (sub == 0) {                            // x2 = dinv[i] * (sum)
            float di = dinv[i];
            float4 r0 = {di * acc[0], di * acc[1], di * acc[2], di * acc[3]};
            float4 r1 = {di * acc[4], di * acc[5], di * acc[6], di * acc[7]};
            ((float4*)h[w])[2 * q]     = r0;
            ((float4*)h[w])[2 * q + 1] = r1;
        }
    }
    __syncthreads();

    if (i < N) {
        float dot = bl[lane];
        const float4* hr = (const float4*)h[w];                  // broadcast
        const float4* wr = (const float4*)(Wl + lane * WPAD);
        #pragma unroll
        for (int t = 0; t < NFEAT / 4; ++t) {
            float4 hv = hr[t], wv = wr[t];
            dot = fmaf(hv.x, wv.x, dot); dot = fmaf(hv.y, wv.y, dot);
            dot = fmaf(hv.z, wv.z, dot); dot = fmaf(hv.w, wv.w, dot);
        }
        float m = dot;
        for (int o = 32; o > 0; o >>= 1) m = fmaxf(m, __shfl_xor(m, o));
        float ex = __expf(dot - m);
        float se = ex;
        for (int o = 32; o > 0; o >>= 1) se += __shfl_xor(se, o);
        out[(size_t)i * NCLS + lane] = dot - m - logf(se);
    }
}

// ---------- launch ----------

static inline size_t align256(size_t v) { return (v + 255) & ~(size_t)255; }

extern "C" void kernel_launch(void* const* d_in, const int* in_sizes, int n_in,
                              void* d_out, int out_size, void* d_ws, size_t ws_size,
                              hipStream_t stream) {
    const float* x  = (const float*)d_in[0];
    const int*   ei = (const int*)d_in[1];
    const float* W  = (const float*)d_in[2];
    const float* b  = (const float*)d_in[3];
    float* out = (float*)d_out;

    const int N = in_sizes[0] / NFEAT;   // 50000
    const int E = in_sizes[1] / 2;       // 800000
    const int* src = ei;
    const int* dst = ei + E;
    const int NB = (N + 255) / 256;      // scan blocks (196 <= 256)

    // padded csr capacity: E + 3 per row + read-overrun slack
    const int CSR_CAP = E + 3 * N + 64;

    char* ws = (char*)d_ws;
    size_t o = 0;
    int*    cnt     = (int*)(ws + o);    o += align256((size_t)N * 4);
    float*  dinv    = (float*)(ws + o);  o += align256((size_t)N * 4);
    int*    row_ptr = (int*)(ws + o);    o += align256((size_t)(N + 1) * 4);
    int*    cursor  = (int*)(ws + o);    o += align256((size_t)N * 4);
    int*    bsums   = (int*)(ws + o);    o += align256(256 * 4);
    int*    csr     = (int*)(ws + o);    o += align256((size_t)CSR_CAP * 4);
    __half* xh      = (__half*)(ws + o); o += align256((size_t)(N + 1) * NFEAT * 2);
    __half* y1h     = (__half*)(ws + o); o += align256((size_t)(N + 1) * NFEAT * 2);

    const int E4 = (E + 3) / 4;
    const int F4 = (CSR_CAP + 3) / 4;

    hipMemsetAsync(cnt, 0, (size_t)N * 4, stream);
    count_kernel<<<(E4 + 255) / 256, 256, 0, stream>>>(dst, cnt, E);
    scan_local<<<NB, 256, 0, stream>>>(cnt, row_ptr, bsums, N);
    scan_finalize<<<NB, 256, 0, stream>>>(cnt, bsums, row_ptr, cursor, dinv, N);
    fill_kernel<<<(F4 + 255) / 256, 256, 0, stream>>>(csr, N, F4);
    scatter_kernel<<<(E4 + 255) / 256, 256, 0, stream>>>(src, dst, cursor, csr, E);
    prep_kernel<<<(N * 32 + 255) / 256, 256, 0, stream>>>(x, dinv, xh, N * 32);
    zero_row_kernel<<<1, 16, 0, stream>>>(xh, N);    // dummy row = 0
    zero_row_kernel<<<1, 16, 0, stream>>>(y1h, N);   // dummy row = 0
    hop1_kernel<<<(N + 7) / 8, 512, 0, stream>>>(xh, dinv, row_ptr, csr, y1h, N);
    hop2_cls_kernel<<<(N + 7) / 8, 512, 0, stream>>>(y1h, dinv, row_ptr, csr, W, b, out, N);
}